// Round 1
// baseline (2642.627 us; speedup 1.0000x reference)
//
#include <hip/hip_runtime.h>
#include <hip/hip_bf16.h>
#include <stdint.h>

// Problem constants
#define B_SZ   64
#define L_SEQ  512
#define DIN    1024
#define HDIM   1024
#define G4     4096   // 4*H
// out layout: outputs [64*512*1024], h_fin [64*1024], c_fin [64*1024]
#define OUT_HFIN 33554432L
#define OUT_CFIN 33619968L

typedef float  f32x4 __attribute__((ext_vector_type(4)));
typedef short  s16x8 __attribute__((ext_vector_type(8)));
typedef unsigned short u16;
typedef unsigned long long u64;

// ---- workspace layout (bytes) ----
#define OFF_XBF   0ULL
#define OFF_WX    67108864ULL
#define OFF_WH    75497472ULL
#define OFF_XPROJ 83886080ULL
#define OFF_HBUF  352321536ULL   // 2 * 64*1024*2 = 262144 (ping-pong)
#define OFF_FLG   352583680ULL   // 4 groups * 64 int flags = 1KB

static __device__ __forceinline__ u16 f2bf(float f) {
    __hip_bfloat16 h = __float2bfloat16(f);
    return *reinterpret_cast<u16*>(&h);
}
static __device__ __forceinline__ float bf2f(u16 u) {
    union { uint32_t i; float f; } v;
    v.i = ((uint32_t)u) << 16;
    return v.f;
}
static __device__ __forceinline__ float fsigmoid(float x) {
    return __builtin_amdgcn_rcpf(1.0f + __expf(-x));
}
static __device__ __forceinline__ float ftanh(float x) {
    return 1.0f - 2.0f * __builtin_amdgcn_rcpf(1.0f + __expf(2.0f * x));
}
// async global->LDS, 16B per lane. LDS ptr must be wave-uniform (HW writes
// base + lane*16); global ptr is per-lane.
static __device__ __forceinline__ void gload_lds16(const u16* g, u16* l) {
    __builtin_amdgcn_global_load_lds((const __attribute__((address_space(1))) void*)g,
                                     (__attribute__((address_space(3))) void*)l, 16, 0, 0);
}

// ============================ prep: fp32 -> bf16 ============================
__global__ void prep_kernel(const float* __restrict__ x, const float* __restrict__ W,
                            u16* __restrict__ xbf, u16* __restrict__ wx,
                            u16* __restrict__ wh, int* __restrict__ flg) {
    long tid = (long)blockIdx.x * blockDim.x + threadIdx.x;
    long stride = (long)gridDim.x * blockDim.x;
    const long NX4 = 33554432 / 4;
    for (long i = tid; i < NX4; i += stride) {
        float4 v = ((const float4*)x)[i];
        ushort4 o;
        o.x = f2bf(v.x); o.y = f2bf(v.y); o.z = f2bf(v.z); o.w = f2bf(v.w);
        ((ushort4*)xbf)[i] = o;
    }
    const long NW4 = 8388608 / 4;
    for (long i = tid; i < NW4; i += stride) {
        float4 v = ((const float4*)W)[i];
        long f = i * 4;
        long n = f >> 11;        // row of W (2048 wide)
        long c = f & 2047;
        ushort4 o;
        o.x = f2bf(v.x); o.y = f2bf(v.y); o.z = f2bf(v.z); o.w = f2bf(v.w);
        u16* dst = (c < 1024) ? &wh[n * 1024 + c] : &wx[n * 1024 + (c - 1024)];
        *(ushort4*)dst = o;
    }
    if (blockIdx.x == 0 && threadIdx.x < 256) flg[threadIdx.x] = 0;
}

// ==================== phase 1: x_proj = x @ Wx^T + b (bf16 out) =============
// m97-structure retrofit: global_load_lds dwordx4 staging + double-buffered
// LDS, one barrier per K-step. BK=32 row-major (stride 64B: 2-way bank
// aliasing only; linear lane order matches global_load_lds's fixed
// base+lane*16 LDS mapping).
__global__ __launch_bounds__(256) void xproj_gemm(const u16* __restrict__ xbf,
                                                  const u16* __restrict__ wxbf,
                                                  const float* __restrict__ bias,
                                                  u16* __restrict__ xproj) {
    __shared__ u16 As[2][128 * 32];
    __shared__ u16 Bs[2][128 * 32];
    const int tid  = threadIdx.x;
    const int lane = tid & 63;
    const int w    = tid >> 6;
    const int wm   = w >> 1, wn = w & 1;
    const int l15  = lane & 15, quad = lane >> 4;
    const int m0 = blockIdx.y * 128;
    const int n0 = blockIdx.x * 128;

    // per-lane global base: row = tid>>2 (64 rows per round), col16B = tid&3
    const u16* ga = xbf  + (long)(m0 + (tid >> 2)) * 1024 + (tid & 3) * 8;
    const u16* gb = wxbf + (long)(n0 + (tid >> 2)) * 1024 + (tid & 3) * 8;

    f32x4 acc[4][4];
#pragma unroll
    for (int i = 0; i < 4; ++i)
#pragma unroll
        for (int j = 0; j < 4; ++j) acc[i][j] = 0.0f;

#define STAGE(buf, k0)                                                    \
    do {                                                                  \
        gload_lds16(ga + (k0),         &As[buf][w * 512]);                \
        gload_lds16(ga + 65536 + (k0), &As[buf][2048 + w * 512]);         \
        gload_lds16(gb + (k0),         &Bs[buf][w * 512]);                \
        gload_lds16(gb + 65536 + (k0), &Bs[buf][2048 + w * 512]);         \
    } while (0)

    STAGE(0, 0);
    __syncthreads();                       // drains stage (compiler vmcnt(0))

    for (int kt = 0; kt < 32; ++kt) {
        const int cur = kt & 1;
        if (kt < 31) STAGE(cur ^ 1, (kt + 1) * 32);   // async prefetch

        s16x8 af[4], bfr[4];
#pragma unroll
        for (int mt = 0; mt < 4; ++mt)
            af[mt] = *(const s16x8*)&As[cur][(wm * 64 + mt * 16 + l15) * 32 + quad * 8];
#pragma unroll
        for (int nt = 0; nt < 4; ++nt)
            bfr[nt] = *(const s16x8*)&Bs[cur][(wn * 64 + nt * 16 + l15) * 32 + quad * 8];
#pragma unroll
        for (int mt = 0; mt < 4; ++mt)
#pragma unroll
            for (int nt = 0; nt < 4; ++nt)
                acc[mt][nt] = __builtin_amdgcn_mfma_f32_16x16x32_bf16(af[mt], bfr[nt], acc[mt][nt], 0, 0, 0);

        __syncthreads();                   // drains prefetch + lds reads
    }
#undef STAGE

#pragma unroll
    for (int nt = 0; nt < 4; ++nt) {
        int n = n0 + wn * 64 + nt * 16 + l15;
        float bv = bias[n];
#pragma unroll
        for (int mt = 0; mt < 4; ++mt) {
            int mbase = m0 + wm * 64 + mt * 16 + quad * 4;
#pragma unroll
            for (int r = 0; r < 4; ++r)
                xproj[(long)(mbase + r) * 4096 + n] = f2bf(acc[mt][nt][r] + bv);
        }
    }
}

// ======================= phase 2: sequential recurrence =====================
// 256 blocks: g = bid&3 (16 batch rows), jc = bid>>2 (16 h-cols).
// Wave w covers K-slice [256w, 256w+256) for ALL 4 gates.
// Changes vs prior version (critical-path shortening):
//   * wave-local flag poll (16 producers per wave, not 64 per block)
//   * h_{t-1} loaded DIRECTLY into A-fragments (per-lane u64 atomic loads,
//     row l15 only) -- no h_s LDS stage, no barrier (A)
//   * out[] HBM store moved AFTER the flag store (off the vmcnt(0) ack path)
__global__ __launch_bounds__(256, 1) void lstm_rec(const u16* __restrict__ whbf,
                                                   const u16* __restrict__ xproj,
                                                   u16* __restrict__ hbuf,
                                                   float* __restrict__ out,
                                                   int* __restrict__ flg) {
    __shared__ float part[4][16][16][4];      // [gate][row][col][wave]
    __shared__ u16   how[4][4][16];           // [wave][rowInWave][col]

    const int tid  = threadIdx.x;
    const int w    = tid >> 6;
    const int lane = tid & 63;
    const int l15  = lane & 15, quad = lane >> 4;
    const int g    = blockIdx.x & 3;
    const int jc   = blockIdx.x >> 2;
    const int bbase = g * 16;
    const int crow = 4 * w + (lane >> 4);     // elementwise cell row (0..15)
    const int ccol = l15;                     // elementwise cell col (0..15)
    int* fl   = flg + g * 64;
    int* myfl = fl + w * 16 + (lane & 15);    // wave-local producer flag

    // Wh fragments: wave w holds K-slice [w*256, w*256+256) for all 4 gates.
    s16x8 bfrag[4][8];
#pragma unroll
    for (int gate = 0; gate < 4; ++gate) {
        const long nrow = (long)gate * 1024 + jc * 16 + l15;
#pragma unroll
        for (int kc = 0; kc < 8; ++kc)
            bfrag[gate][kc] = *(const s16x8*)&whbf[nrow * 1024 + w * 256 + kc * 32 + quad * 8];
    }

    float c_reg = 0.0f;
    u64* hb64[2] = { (u64*)hbuf, (u64*)(hbuf + 65536) };
    // per-lane h source: row (bbase+l15), cols w*256 + quad*8 + kc*32 (u64 idx)
    const long rbase = (((long)(bbase + l15)) * 1024 + w * 256 + quad * 8) >> 2;

    // xp prefetch for t=0: per-lane, its cell, 4 gates
    const u16* xpcell = xproj + (long)(bbase + crow) * 512 * 4096 + jc * 16 + ccol;
    float xp[4];
#pragma unroll
    for (int gate = 0; gate < 4; ++gate)
        xp[gate] = bf2f(xpcell[(long)gate * 1024]);

    for (int t = 0; t < 512; ++t) {
        // ---- acquire h_{t-1} directly into A-fragments ----
        union AF { u64 d[2]; s16x8 v; } af[8];
        if (t == 0) {
#pragma unroll
            for (int kc = 0; kc < 8; ++kc) { af[kc].d[0] = 0ULL; af[kc].d[1] = 0ULL; }
        } else {
            // wave-local poll: this wave only needs producers jc'=[16w,16w+16)
            int pv = __hip_atomic_load(myfl, __ATOMIC_RELAXED, __HIP_MEMORY_SCOPE_AGENT);
            while (__ballot(pv < t) != 0ULL) {
                __builtin_amdgcn_s_sleep(1);
                pv = __hip_atomic_load(myfl, __ATOMIC_RELAXED, __HIP_MEMORY_SCOPE_AGENT);
            }
            const u64* hsrc = hb64[(t + 1) & 1];
#pragma unroll
            for (int kc = 0; kc < 8; ++kc) {
                af[kc].d[0] = __hip_atomic_load(&hsrc[rbase + kc * 8],
                                                __ATOMIC_RELAXED, __HIP_MEMORY_SCOPE_AGENT);
                af[kc].d[1] = __hip_atomic_load(&hsrc[rbase + kc * 8 + 1],
                                                __ATOMIC_RELAXED, __HIP_MEMORY_SCOPE_AGENT);
            }
        }

        // ---- MFMA: K-slice per wave, 4 gate accumulators ----
        f32x4 acc[4];
#pragma unroll
        for (int gate = 0; gate < 4; ++gate) acc[gate] = 0.0f;
#pragma unroll
        for (int kc = 0; kc < 8; ++kc) {
            s16x8 a = af[kc].v;
            acc[0] = __builtin_amdgcn_mfma_f32_16x16x32_bf16(a, bfrag[0][kc], acc[0], 0, 0, 0);
            acc[1] = __builtin_amdgcn_mfma_f32_16x16x32_bf16(a, bfrag[1][kc], acc[1], 0, 0, 0);
            acc[2] = __builtin_amdgcn_mfma_f32_16x16x32_bf16(a, bfrag[2][kc], acc[2], 0, 0, 0);
            acc[3] = __builtin_amdgcn_mfma_f32_16x16x32_bf16(a, bfrag[3][kc], acc[3], 0, 0, 0);
        }
        // partial sums to LDS: D row = quad*4+r, col = l15
#pragma unroll
        for (int gate = 0; gate < 4; ++gate)
#pragma unroll
            for (int r = 0; r < 4; ++r)
                part[gate][quad * 4 + r][l15][w] = acc[gate][r];
        __syncthreads();   // (B) partials ready

        // ---- elementwise: each lane owns one (crow, ccol) cell ----
        float gv[4];
#pragma unroll
        for (int gate = 0; gate < 4; ++gate) {
            f32x4 p = *(const f32x4*)&part[gate][crow][ccol][0];
            gv[gate] = ((p[0] + p[1]) + (p[2] + p[3])) + xp[gate];
        }
        float fv = fsigmoid(gv[0]);
        float iv = fsigmoid(gv[1]);
        float gg = ftanh   (gv[2]);
        float ov = fsigmoid(gv[3]);
        c_reg = fv * c_reg + iv * gg;
        float h = ov * ftanh(c_reg);

        if (t < 511) {
            // critical path: h packet -> ack -> barrier -> flag. out store is
            // issued AFTER the flag so its HBM ack is not inside the drain.
            how[w][lane >> 4][ccol] = f2bf(h);
            if (lane < 16) {
                int prow = 4 * w + (lane >> 2);
                int c4   = (lane & 3) * 4;
                u64 hv = *(const u64*)&how[w][lane >> 2][c4];
                __hip_atomic_store(&hb64[t & 1][((long)(bbase + prow) * 1024 + jc * 16 + c4) >> 2],
                                   hv, __ATOMIC_RELAXED, __HIP_MEMORY_SCOPE_AGENT);
            }
            __asm__ volatile("s_waitcnt vmcnt(0)" ::: "memory");  // h stores acked
            __syncthreads();   // (C) all waves drained
            if (tid == 0)
                __hip_atomic_store(&fl[jc], t + 1, __ATOMIC_RELAXED, __HIP_MEMORY_SCOPE_AGENT);
        }

        long bg = bbase + crow;
        long j  = jc * 16 + ccol;
        out[(bg * 512 + t) * 1024 + j] = h;
        if (t == 511) {
            out[OUT_HFIN + bg * 1024 + j] = h;
            out[OUT_CFIN + bg * 1024 + j] = c_reg;
        } else {
            // xp prefetch for t+1 (after flag: off the critical path)
#pragma unroll
            for (int gate = 0; gate < 4; ++gate)
                xp[gate] = bf2f(xpcell[((long)t + 1) * 4096 + (long)gate * 1024]);
        }
    }
}

// ================================ launcher =================================
extern "C" void kernel_launch(void* const* d_in, const int* in_sizes, int n_in,
                              void* d_out, int out_size, void* d_ws, size_t ws_size,
                              hipStream_t stream) {
    const float* x    = (const float*)d_in[0];
    const float* W    = (const float*)d_in[1];
    const float* bias = (const float*)d_in[2];
    float* out = (float*)d_out;
    char*  ws  = (char*)d_ws;

    u16* xbf   = (u16*)(ws + OFF_XBF);
    u16* wx    = (u16*)(ws + OFF_WX);
    u16* wh    = (u16*)(ws + OFF_WH);
    u16* xproj = (u16*)(ws + OFF_XPROJ);
    u16* hbuf  = (u16*)(ws + OFF_HBUF);
    int* flg   = (int*)(ws + OFF_FLG);

    hipLaunchKernelGGL(prep_kernel, dim3(2048), dim3(256), 0, stream, x, W, xbf, wx, wh, flg);
    hipLaunchKernelGGL(xproj_gemm, dim3(32, 256), dim3(256), 0, stream, xbf, wx, bias, xproj);
    hipLaunchKernelGGL(lstm_rec, dim3(256), dim3(256), 0, stream, wh, xproj, hbuf, out, flg);
}